// Round 4
// baseline (179.335 us; speedup 1.0000x reference)
//
#include <hip/hip_runtime.h>
#include <hip/hip_fp16.h>

#define BB 8
#define NN 8192
#define SS 2048
#define CC 256
#define KNN 8
#define TOPM 10       // per-list candidate count (top-8 + margin 2 for key ties)
#define NLIST 4       // 4 lists per query (one per 16-lane MFMA row group)
#define QPB 64        // queries per block (16 per wave x 4 waves)
#define MSTRIDE 41    // mbuf per-query stride (u32s): 41 mod 32 = 9 -> conflict-free
#define TSTR 264      // prep2 LDS row stride in halves (528 B, 16B-aligned)

#define UMIN(a, b) __builtin_elementwise_min(a, b)
#define UMAX(a, b) __builtin_elementwise_max(a, b)
#define UMIN3(a, b, c) UMIN(UMIN(a, b), c)

typedef short bf16x8_t __attribute__((ext_vector_type(8)));   // 8 bf16 = 4 VGPR
typedef float f32x4_t __attribute__((ext_vector_type(4)));

__device__ __forceinline__ float2 unpack_h2(unsigned u) {
    __half2 h = *reinterpret_cast<__half2*>(&u);
    return __half22float2(h);
}

// f32 -> bf16 (RNE) and back, bit-level
__device__ __forceinline__ unsigned short f2bf(float f) {
    unsigned u = __float_as_uint(f);
    u += 0x7FFFu + ((u >> 16) & 1u);
    return (unsigned short)(u >> 16);
}
__device__ __forceinline__ float bf2f(unsigned short h) {
    return __uint_as_float((unsigned)h << 16);
}

// merge an unordered pair (ca,cb) into ascending top-10 list (proven net)
__device__ __forceinline__ void ins2(unsigned k1[TOPM], unsigned ca, unsigned cb) {
    unsigned lo = UMIN(ca, cb), hi = UMAX(ca, cb);
#pragma unroll
    for (int j = TOPM - 1; j >= 2; --j)
        k1[j] = UMIN3(k1[j], UMAX(k1[j - 1], lo), UMAX(k1[j - 2], hi));
    k1[1] = UMIN3(k1[1], UMAX(k1[0], lo), hi);
    k1[0] = UMIN(k1[0], lo);
}

__device__ __forceinline__ void ins_step(unsigned k1[TOPM], f32x4_t d, unsigned sbase) {
    // key = truncated distance bits | point index (11 bits); d > 0 guaranteed (bias)
    unsigned c0 = (__float_as_uint(d[0]) & 0xFFFFF800u) | sbase;
    unsigned c1 = (__float_as_uint(d[1]) & 0xFFFFF800u) | (sbase + 1u);
    unsigned c2 = (__float_as_uint(d[2]) & 0xFFFFF800u) | (sbase + 2u);
    unsigned c3 = (__float_as_uint(d[3]) & 0xFFFFF800u) | (sbase + 3u);
    ins2(k1, c0, c1);
    ins2(k1, c2, c3);
}

// ---------------- Kernel P1: build split-bf16 A-tiles in global (512 KB) ----
__global__ __launch_bounds__(256) void prep_kernel(
    const float* __restrict__ sxyz,        // [B,3,S]
    unsigned short* __restrict__ gt)       // [B][2][SS][8]
{
    const int b = blockIdx.x;
    const int tid = threadIdx.x;
    const float* sb = sxyz + (long)b * 3 * SS;
    unsigned short* gb = gt + (long)b * 2 * SS * 8;
#pragma unroll
    for (int i = 0; i < SS / 256; ++i) {
        int s = i * 256 + tid;
        float px = sb[s], py = sb[SS + s], pz = sb[2 * SS + s];
        unsigned short xh = f2bf(px); unsigned short xl = f2bf(px - bf2f(xh));
        unsigned short yh = f2bf(py); unsigned short yl = f2bf(py - bf2f(yh));
        unsigned short zh = f2bf(pz); unsigned short zl = f2bf(pz - bf2f(zh));
        float pn = fmaf(px, px, fmaf(py, py, pz * pz));
        unsigned short nh = f2bf(pn); unsigned short nl = f2bf(pn - bf2f(nh));
        const unsigned ONE = 0x3F80u;
        // k0..7  = [xh, xl, xh, yh, yl, yh, zh, zl]
        uint4 t0 = make_uint4((unsigned)xh | ((unsigned)xl << 16),
                              (unsigned)xh | ((unsigned)yh << 16),
                              (unsigned)yl | ((unsigned)yh << 16),
                              (unsigned)zh | ((unsigned)zl << 16));
        // k8..15 = [zh, nh, nl, 1, 1, 0, 0, 0]
        uint4 t1 = make_uint4((unsigned)zh | ((unsigned)nh << 16),
                              (unsigned)nl | (ONE << 16),
                              ONE, 0u);
        *(uint4*)&gb[(long)s * 8] = t0;
        *(uint4*)&gb[((long)SS + s) * 8] = t1;
    }
}

// ---------------- Kernel P2: transpose sf [B,C,S] f32 -> sfT [B,S,C] f16 ----
// Block = (b, 64-point s-tile). Coalesced row reads, LDS transpose, 16B writes.
__global__ __launch_bounds__(256) void prep2_kernel(
    const float* __restrict__ sf,          // [B,C,S]
    unsigned short* __restrict__ sft)      // [B][S][C] f16
{
    __shared__ unsigned short ts[64 * TSTR];   // 33 KB

    const int blk = blockIdx.x;
    const int b   = blk >> 5;
    const int st  = blk & 31;                  // s-tile (64 points)
    const int t   = threadIdx.x;

    // read: per iter, 4 channel-rows x 64 consecutive s (coalesced dwords)
    const int s  = t & 63;
    const int cq = t >> 6;                     // 0..3
    const float* sfb = sf + (long)b * CC * SS + (long)st * 64;
#pragma unroll
    for (int it = 0; it < CC / 4; ++it) {
        int c = it * 4 + cq;
        float v = sfb[(long)c * SS + s];
        ts[s * TSTR + c] = __half_as_ushort(__float2half_rn(v));
    }
    __syncthreads();

    // write: thread -> (s-row, 64-ch chunk); 8 x 16B contiguous stores
    const int so = t >> 2;
    const int co = (t & 3) * 64;
    unsigned short* dst = sft + ((long)b * SS + st * 64 + so) * CC + co;
    const unsigned short* src = &ts[so * TSTR + co];
#pragma unroll
    for (int i = 0; i < 8; ++i)
        *(uint4*)&dst[i * 8] = *(const uint4*)&src[i * 8];
}

// ---------------- Kernel A: MFMA KNN + fused IDW feature accumulation -------
// Phase 1: 128 MFMA steps (round-2 form, depth-1 prefetch). Phase 2: f64
// re-rank -> (f16 w | idx) in LDS. Phase 3 (fused): all 256 threads gather
// sfT rows from L2 (64B-coalesced per query-group) and write out directly.
__global__ __launch_bounds__(256, 4) void knn_kernel(
    const float* __restrict__ xyz,         // [B,3,N]
    const float* __restrict__ sxyz,        // [B,3,S]
    const unsigned short* __restrict__ gt, // [B][2][SS][8] split-bf16 tiles
    const unsigned short* __restrict__ sft,// [B][S][C] f16 features
    float* __restrict__ out)               // [B,C,N]
{
    __shared__ unsigned mbuf[QPB * MSTRIDE];          // 10.25 KB
    __shared__ unsigned pk_lds[QPB * KNN];            // 2 KB

    const int b    = blockIdx.x >> 7;                 // 128 blocks per batch
    const int q0   = (blockIdx.x & 127) * QPB;
    const int tid  = threadIdx.x;
    const int wave = tid >> 6;
    const int lane = tid & 63;
    const int g    = lane >> 4;                       // MFMA row group / list id
    const int qi   = lane & 15;                       // query-in-wave / A-row

    const float* sb = sxyz + (long)b * 3 * SS;
    const float* xb = xyz + (long)b * 3 * NN;

    // ---- per-lane query B-fragment (col = lane&15, k = 8*g + e) ------------
    const int nq = q0 + wave * 16 + qi;
    const float qx = xb[nq], qy = xb[NN + nq], qz = xb[2 * NN + nq];

    bf16x8_t qf = (bf16x8_t)0;
    {
        unsigned short xh = f2bf(qx); float xhf = bf2f(xh);
        unsigned short yh = f2bf(qy); float yhf = bf2f(yh);
        unsigned short zh = f2bf(qz); float zhf = bf2f(zh);
        unsigned short xh2 = f2bf(-2.f * xhf), xl2 = f2bf(-2.f * (qx - xhf));
        unsigned short yh2 = f2bf(-2.f * yhf), yl2 = f2bf(-2.f * (qy - yhf));
        unsigned short zh2 = f2bf(-2.f * zhf), zl2 = f2bf(-2.f * (qz - zhf));
        float qn = fmaf(qx, qx, fmaf(qy, qy, qz * qz)) + 0.0625f;  // bias keeps d>0
        unsigned short nh = f2bf(qn); unsigned short nl = f2bf(qn - bf2f(nh));
        const short ONE = (short)0x3F80;
        if (g == 0) {
            qf[0] = (short)xh2; qf[1] = (short)xh2; qf[2] = (short)xl2;
            qf[3] = (short)yh2; qf[4] = (short)yh2; qf[5] = (short)yl2;
            qf[6] = (short)zh2; qf[7] = (short)zh2;
        } else if (g == 1) {
            qf[0] = (short)zl2; qf[1] = ONE; qf[2] = ONE;
            qf[3] = (short)nh;  qf[4] = (short)nl;
        } // g>=2: zero fragment (k16..31 unused -> A-slices don't matter)
    }

    // ---- phase 1: 128 MFMA steps, depth-1 software pipeline (round-2 form) -
    const unsigned short* ap =
        gt + (long)b * 2 * SS * 8 + (long)(g & 1) * SS * 8 + qi * 8;

    unsigned k1[TOPM];
#pragma unroll
    for (int j = 0; j < TOPM; ++j) k1[j] = 0xFFFFFFFFu;

    const f32x4_t zacc = {0.f, 0.f, 0.f, 0.f};
    const unsigned ib4 = (unsigned)(g * 4);

    bf16x8_t af = *(const bf16x8_t*)ap; ap += 128;
    f32x4_t dc = __builtin_amdgcn_mfma_f32_16x16x32_bf16(af, qf, zacc, 0, 0, 0);

#pragma unroll 2
    for (int step = 0; step < 127; ++step) {
        bf16x8_t an = *(const bf16x8_t*)ap; ap += 128;
        f32x4_t dn = __builtin_amdgcn_mfma_f32_16x16x32_bf16(an, qf, zacc, 0, 0, 0);
        ins_step(k1, dc, ib4 + (unsigned)(step * 16));
        dc = dn;
    }
    ins_step(k1, dc, ib4 + (unsigned)(127 * 16));

    {
        unsigned* m1 = &mbuf[(wave * 16 + qi) * MSTRIDE + g * TOPM];
#pragma unroll
        for (int j = 0; j < TOPM; ++j) m1[j] = k1[j];
    }
    __syncthreads();

    // ---- phase 2: one thread per query, f64 re-rank of 40 candidates ------
    if (tid < QPB) {
        const int n2 = q0 + tid;
        const double dqx = (double)xb[n2], dqy = (double)xb[NN + n2], dqz = (double)xb[2 * NN + n2];
        const unsigned* ml = &mbuf[tid * MSTRIDE];

        unsigned long long top[KNN];
#pragma unroll
        for (int j = 0; j < KNN; ++j) top[j] = ~0ull;

#pragma unroll 4
        for (int j = 0; j < NLIST * TOPM; ++j) {
            unsigned key = ml[j];
            int s = key & 0x7FF;
            float px = sb[s], py = sb[SS + s], pz = sb[2 * SS + s];  // L2-hot
            double ex = (double)px - dqx;
            double ey = (double)py - dqy;
            double ez = (double)pz - dqz;
            double dd = ex * ex + ey * ey + ez * ez;
            unsigned long long c =
                (((unsigned long long)__double_as_longlong(dd)) & ~0x7FFull) | (unsigned long long)s;
#pragma unroll
            for (int jj = KNN - 1; jj >= 1; --jj)
                top[jj] = UMIN(UMAX(top[jj - 1], c), top[jj]);
            top[0] = UMIN(top[0], c);
        }

        // IDW weights (f32 math, f16-rounded weight as before)
        const float fqx = xb[n2], fqy = xb[NN + n2], fqz = xb[2 * NN + n2];
        int   id[KNN];
        float inv[KNN];
        float ssum = 0.f;
#pragma unroll
        for (int k = 0; k < KNN; ++k) {
            id[k] = (int)(top[k] & 0x7FFull);
            float px = sb[id[k]], py = sb[SS + id[k]], pz = sb[2 * SS + id[k]];
            float dx = px - fqx, dy = py - fqy, dz = pz - fqz;
            float dv = sqrtf(dx * dx + dy * dy + dz * dz);
            dv = fmaxf(dv, 1e-10f);
            inv[k] = 1.0f / dv;
            ssum += inv[k];
        }
        const float rs = 1.0f / ssum;
#pragma unroll
        for (int k = 0; k < KNN; ++k) {
            unsigned hw = (unsigned)__half_as_ushort(__float2half_rn(inv[k] * rs));
            pk_lds[tid * KNN + k] = (hw << 16) | (unsigned)id[k];
        }
    }
    __syncthreads();

    // ---- phase 3 (fused accum): thread = (query q, channel-lane cl) --------
    // Per k, the 4 cl-lanes of a q-group read 4x16B consecutive halves of
    // sfT[b][id] (64B-coalesced L2 hits); 8 chunks cover all 256 channels.
    {
        const int q  = tid >> 2;
        const int cl = tid & 3;
        const unsigned short* sfb = sft + (long)b * SS * CC;
        float* outq = out + (long)b * CC * NN + (q0 + q);

        unsigned pks[KNN];
#pragma unroll
        for (int k = 0; k < KNN; ++k) pks[k] = pk_lds[q * KNN + k];  // LDS broadcast

#pragma unroll
        for (int cc = 0; cc < 8; ++cc) {
            const int ch = cc * 32 + cl * 8;
            float acc[8];
#pragma unroll
            for (int j = 0; j < 8; ++j) acc[j] = 0.f;

#pragma unroll
            for (int k = 0; k < KNN; ++k) {
                const unsigned p = pks[k];
                const int idp = p & 0x7FF;
                const float w = __half2float(__ushort_as_half((unsigned short)(p >> 16)));
                const uint4 F = *(const uint4*)&sfb[(long)idp * CC + ch];  // 16B = 8 ch
                float2 f0 = unpack_h2(F.x), f1 = unpack_h2(F.y);
                float2 f2 = unpack_h2(F.z), f3 = unpack_h2(F.w);
                acc[0] = fmaf(w, f0.x, acc[0]);
                acc[1] = fmaf(w, f0.y, acc[1]);
                acc[2] = fmaf(w, f1.x, acc[2]);
                acc[3] = fmaf(w, f1.y, acc[3]);
                acc[4] = fmaf(w, f2.x, acc[4]);
                acc[5] = fmaf(w, f2.y, acc[5]);
                acc[6] = fmaf(w, f3.x, acc[6]);
                acc[7] = fmaf(w, f3.y, acc[7]);
            }
#pragma unroll
            for (int j = 0; j < 8; ++j)
                outq[(long)(ch + j) * NN] = acc[j];   // 16 consecutive n per wave row
        }
    }
}

extern "C" void kernel_launch(void* const* d_in, const int* in_sizes, int n_in,
                              void* d_out, int out_size, void* d_ws, size_t ws_size,
                              hipStream_t stream) {
    const float* xyz  = (const float*)d_in[0];   // [8,3,8192]
    const float* sxyz = (const float*)d_in[1];   // [8,3,2048]
    const float* sf   = (const float*)d_in[2];   // [8,256,2048]
    float* out = (float*)d_out;                  // [8,256,8192]

    unsigned short* gtile = (unsigned short*)d_ws;                        // 512 KB
    unsigned short* sft   = (unsigned short*)((char*)d_ws + 512 * 1024);  // 8 MB

    prep_kernel<<<dim3(BB), dim3(256), 0, stream>>>(sxyz, gtile);
    prep2_kernel<<<dim3(BB * 32), dim3(256), 0, stream>>>(sf, sft);
    knn_kernel<<<dim3(BB * NN / QPB), dim3(256), 0, stream>>>(xyz, sxyz, gtile, sft, out);
}

// Round 5
// 174.350 us; speedup vs baseline: 1.0286x; 1.0286x over previous
//
#include <hip/hip_runtime.h>
#include <hip/hip_fp16.h>

#define BB 8
#define NN 8192
#define SS 2048
#define CC 256
#define KNN 8
#define TOPM 10       // per-list candidate count (top-8 + margin 2 for key ties)
#define NLIST 4       // 4 lists per query (one per 16-lane MFMA row group)
#define QPB 64        // queries per block (16 per wave x 4 waves)
#define MSTRIDE 41    // mbuf per-query stride (u32s): 41 mod 32 = 9 -> conflict-free
#define P2STR 66      // prep2 LDS stride in halves: dword stride 33 (odd) -> conflict-free

#define UMIN(a, b) __builtin_elementwise_min(a, b)
#define UMAX(a, b) __builtin_elementwise_max(a, b)
#define UMIN3(a, b, c) UMIN(UMIN(a, b), c)

typedef short bf16x8_t __attribute__((ext_vector_type(8)));   // 8 bf16 = 4 VGPR
typedef float f32x4_t __attribute__((ext_vector_type(4)));

__device__ __forceinline__ float2 unpack_h2(unsigned u) {
    __half2 h = *reinterpret_cast<__half2*>(&u);
    return __half22float2(h);
}

// f32 -> bf16 (RNE) and back, bit-level
__device__ __forceinline__ unsigned short f2bf(float f) {
    unsigned u = __float_as_uint(f);
    u += 0x7FFFu + ((u >> 16) & 1u);
    return (unsigned short)(u >> 16);
}
__device__ __forceinline__ float bf2f(unsigned short h) {
    return __uint_as_float((unsigned)h << 16);
}

// merge an unordered pair (ca,cb) into ascending top-10 list (proven net)
__device__ __forceinline__ void ins2(unsigned k1[TOPM], unsigned ca, unsigned cb) {
    unsigned lo = UMIN(ca, cb), hi = UMAX(ca, cb);
#pragma unroll
    for (int j = TOPM - 1; j >= 2; --j)
        k1[j] = UMIN3(k1[j], UMAX(k1[j - 1], lo), UMAX(k1[j - 2], hi));
    k1[1] = UMIN3(k1[1], UMAX(k1[0], lo), hi);
    k1[0] = UMIN(k1[0], lo);
}

__device__ __forceinline__ void ins_step(unsigned k1[TOPM], f32x4_t d, unsigned sbase) {
    // key = truncated distance bits | point index (11 bits); d > 0 guaranteed (bias)
    unsigned c0 = (__float_as_uint(d[0]) & 0xFFFFF800u) | sbase;
    unsigned c1 = (__float_as_uint(d[1]) & 0xFFFFF800u) | (sbase + 1u);
    unsigned c2 = (__float_as_uint(d[2]) & 0xFFFFF800u) | (sbase + 2u);
    unsigned c3 = (__float_as_uint(d[3]) & 0xFFFFF800u) | (sbase + 3u);
    ins2(k1, c0, c1);
    ins2(k1, c2, c3);
}

// ---------------- Kernel P: fused prep ---------------------------------------
// Blocks 0..1023:  64s x 64c tile transpose sf [B,C,S] f32 -> sfT [B,S,C] f16.
//   Coalesced 256B/wave channel-row reads; LDS stride-33-dword staging
//   (conflict-free ushort scatter, 2-way free readback); dwordx4 stores.
// Blocks 1024..1087: build split-bf16 MFMA A-tiles gt [B][2][SS][8] (8/batch).
__global__ __launch_bounds__(256) void prep_kernel(
    const float* __restrict__ sf,          // [B,C,S]
    const float* __restrict__ sxyz,        // [B,3,S]
    unsigned short* __restrict__ sft,      // [B][S][C] f16
    unsigned short* __restrict__ gt)       // [B][2][SS][8]
{
    __shared__ unsigned short ts[64 * P2STR];   // 8.25 KB

    const int blk = blockIdx.x;
    const int t   = threadIdx.x;

    if (blk < BB * 32 * 4) {
        // ---- transpose tile: b, s-tile (64 pts), c-tile (64 ch) -----------
        const int b  = blk >> 7;
        const int st = (blk >> 2) & 31;
        const int c0 = (blk & 3) * 64;

        const int s  = t & 63;       // lane within wave
        const int cq = t >> 6;       // wave -> channel offset quarter
        const float* sfb = sf + ((long)b * CC + c0) * SS + st * 64;
#pragma unroll
        for (int it = 0; it < 16; ++it) {
            int c = it * 4 + cq;     // relative channel 0..63
            float v = sfb[(long)c * SS + s];                 // 256B/wave coalesced
            ts[s * P2STR + c] = __half_as_ushort(__float2half_rn(v));
        }
        __syncthreads();

        // write: thread = (row so = t>>2, 16-half chunk cl = t&3)
        const int so = t >> 2;
        const int cl = t & 3;
        const unsigned short* src = &ts[so * P2STR + cl * 16];  // 4B-aligned
        unsigned u[8];
#pragma unroll
        for (int i = 0; i < 8; ++i) u[i] = *(const unsigned*)&src[i * 2];
        unsigned short* dst = sft + ((long)b * SS + st * 64 + so) * CC + c0 + cl * 16;
        *(uint4*)&dst[0] = make_uint4(u[0], u[1], u[2], u[3]);
        *(uint4*)&dst[8] = make_uint4(u[4], u[5], u[6], u[7]);
    } else {
        // ---- gt build: 64 blocks, (b, s-slab of 256) ----------------------
        const int idx = blk - BB * 32 * 4;
        const int b = idx >> 3;
        const int s = (idx & 7) * 256 + t;
        const float* sb = sxyz + (long)b * 3 * SS;
        unsigned short* gb = gt + (long)b * 2 * SS * 8;

        float px = sb[s], py = sb[SS + s], pz = sb[2 * SS + s];
        unsigned short xh = f2bf(px); unsigned short xl = f2bf(px - bf2f(xh));
        unsigned short yh = f2bf(py); unsigned short yl = f2bf(py - bf2f(yh));
        unsigned short zh = f2bf(pz); unsigned short zl = f2bf(pz - bf2f(zh));
        float pn = fmaf(px, px, fmaf(py, py, pz * pz));
        unsigned short nh = f2bf(pn); unsigned short nl = f2bf(pn - bf2f(nh));
        const unsigned ONE = 0x3F80u;
        // k0..7  = [xh, xl, xh, yh, yl, yh, zh, zl]
        uint4 t0 = make_uint4((unsigned)xh | ((unsigned)xl << 16),
                              (unsigned)xh | ((unsigned)yh << 16),
                              (unsigned)yl | ((unsigned)yh << 16),
                              (unsigned)zh | ((unsigned)zl << 16));
        // k8..15 = [zh, nh, nl, 1, 1, 0, 0, 0]
        uint4 t1 = make_uint4((unsigned)zh | ((unsigned)nh << 16),
                              (unsigned)nl | (ONE << 16),
                              ONE, 0u);
        *(uint4*)&gb[(long)s * 8] = t0;
        *(uint4*)&gb[((long)SS + s) * 8] = t1;
    }
}

// ---------------- Kernel A: MFMA KNN + fused IDW feature accumulation -------
// (unchanged from round 4)
__global__ __launch_bounds__(256, 4) void knn_kernel(
    const float* __restrict__ xyz,         // [B,3,N]
    const float* __restrict__ sxyz,        // [B,3,S]
    const unsigned short* __restrict__ gt, // [B][2][SS][8] split-bf16 tiles
    const unsigned short* __restrict__ sft,// [B][S][C] f16 features
    float* __restrict__ out)               // [B,C,N]
{
    __shared__ unsigned mbuf[QPB * MSTRIDE];          // 10.25 KB
    __shared__ unsigned pk_lds[QPB * KNN];            // 2 KB

    const int b    = blockIdx.x >> 7;                 // 128 blocks per batch
    const int q0   = (blockIdx.x & 127) * QPB;
    const int tid  = threadIdx.x;
    const int wave = tid >> 6;
    const int lane = tid & 63;
    const int g    = lane >> 4;                       // MFMA row group / list id
    const int qi   = lane & 15;                       // query-in-wave / A-row

    const float* sb = sxyz + (long)b * 3 * SS;
    const float* xb = xyz + (long)b * 3 * NN;

    // ---- per-lane query B-fragment (col = lane&15, k = 8*g + e) ------------
    const int nq = q0 + wave * 16 + qi;
    const float qx = xb[nq], qy = xb[NN + nq], qz = xb[2 * NN + nq];

    bf16x8_t qf = (bf16x8_t)0;
    {
        unsigned short xh = f2bf(qx); float xhf = bf2f(xh);
        unsigned short yh = f2bf(qy); float yhf = bf2f(yh);
        unsigned short zh = f2bf(qz); float zhf = bf2f(zh);
        unsigned short xh2 = f2bf(-2.f * xhf), xl2 = f2bf(-2.f * (qx - xhf));
        unsigned short yh2 = f2bf(-2.f * yhf), yl2 = f2bf(-2.f * (qy - yhf));
        unsigned short zh2 = f2bf(-2.f * zhf), zl2 = f2bf(-2.f * (qz - zhf));
        float qn = fmaf(qx, qx, fmaf(qy, qy, qz * qz)) + 0.0625f;  // bias keeps d>0
        unsigned short nh = f2bf(qn); unsigned short nl = f2bf(qn - bf2f(nh));
        const short ONE = (short)0x3F80;
        if (g == 0) {
            qf[0] = (short)xh2; qf[1] = (short)xh2; qf[2] = (short)xl2;
            qf[3] = (short)yh2; qf[4] = (short)yh2; qf[5] = (short)yl2;
            qf[6] = (short)zh2; qf[7] = (short)zh2;
        } else if (g == 1) {
            qf[0] = (short)zl2; qf[1] = ONE; qf[2] = ONE;
            qf[3] = (short)nh;  qf[4] = (short)nl;
        } // g>=2: zero fragment (k16..31 unused -> A-slices don't matter)
    }

    // ---- phase 1: 128 MFMA steps, depth-1 software pipeline ----------------
    const unsigned short* ap =
        gt + (long)b * 2 * SS * 8 + (long)(g & 1) * SS * 8 + qi * 8;

    unsigned k1[TOPM];
#pragma unroll
    for (int j = 0; j < TOPM; ++j) k1[j] = 0xFFFFFFFFu;

    const f32x4_t zacc = {0.f, 0.f, 0.f, 0.f};
    const unsigned ib4 = (unsigned)(g * 4);

    bf16x8_t af = *(const bf16x8_t*)ap; ap += 128;
    f32x4_t dc = __builtin_amdgcn_mfma_f32_16x16x32_bf16(af, qf, zacc, 0, 0, 0);

#pragma unroll 2
    for (int step = 0; step < 127; ++step) {
        bf16x8_t an = *(const bf16x8_t*)ap; ap += 128;
        f32x4_t dn = __builtin_amdgcn_mfma_f32_16x16x32_bf16(an, qf, zacc, 0, 0, 0);
        ins_step(k1, dc, ib4 + (unsigned)(step * 16));
        dc = dn;
    }
    ins_step(k1, dc, ib4 + (unsigned)(127 * 16));

    {
        unsigned* m1 = &mbuf[(wave * 16 + qi) * MSTRIDE + g * TOPM];
#pragma unroll
        for (int j = 0; j < TOPM; ++j) m1[j] = k1[j];
    }
    __syncthreads();

    // ---- phase 2: one thread per query, f64 re-rank of 40 candidates ------
    if (tid < QPB) {
        const int n2 = q0 + tid;
        const double dqx = (double)xb[n2], dqy = (double)xb[NN + n2], dqz = (double)xb[2 * NN + n2];
        const unsigned* ml = &mbuf[tid * MSTRIDE];

        unsigned long long top[KNN];
#pragma unroll
        for (int j = 0; j < KNN; ++j) top[j] = ~0ull;

#pragma unroll 4
        for (int j = 0; j < NLIST * TOPM; ++j) {
            unsigned key = ml[j];
            int s = key & 0x7FF;
            float px = sb[s], py = sb[SS + s], pz = sb[2 * SS + s];  // L2-hot
            double ex = (double)px - dqx;
            double ey = (double)py - dqy;
            double ez = (double)pz - dqz;
            double dd = ex * ex + ey * ey + ez * ez;
            unsigned long long c =
                (((unsigned long long)__double_as_longlong(dd)) & ~0x7FFull) | (unsigned long long)s;
#pragma unroll
            for (int jj = KNN - 1; jj >= 1; --jj)
                top[jj] = UMIN(UMAX(top[jj - 1], c), top[jj]);
            top[0] = UMIN(top[0], c);
        }

        // IDW weights (f32 math, f16-rounded weight as before)
        const float fqx = xb[n2], fqy = xb[NN + n2], fqz = xb[2 * NN + n2];
        int   id[KNN];
        float inv[KNN];
        float ssum = 0.f;
#pragma unroll
        for (int k = 0; k < KNN; ++k) {
            id[k] = (int)(top[k] & 0x7FFull);
            float px = sb[id[k]], py = sb[SS + id[k]], pz = sb[2 * SS + id[k]];
            float dx = px - fqx, dy = py - fqy, dz = pz - fqz;
            float dv = sqrtf(dx * dx + dy * dy + dz * dz);
            dv = fmaxf(dv, 1e-10f);
            inv[k] = 1.0f / dv;
            ssum += inv[k];
        }
        const float rs = 1.0f / ssum;
#pragma unroll
        for (int k = 0; k < KNN; ++k) {
            unsigned hw = (unsigned)__half_as_ushort(__float2half_rn(inv[k] * rs));
            pk_lds[tid * KNN + k] = (hw << 16) | (unsigned)id[k];
        }
    }
    __syncthreads();

    // ---- phase 3 (fused accum): thread = (query q, channel-lane cl) --------
    {
        const int q  = tid >> 2;
        const int cl = tid & 3;
        const unsigned short* sfb = sft + (long)b * SS * CC;
        float* outq = out + (long)b * CC * NN + (q0 + q);

        unsigned pks[KNN];
#pragma unroll
        for (int k = 0; k < KNN; ++k) pks[k] = pk_lds[q * KNN + k];  // LDS broadcast

#pragma unroll
        for (int cc = 0; cc < 8; ++cc) {
            const int ch = cc * 32 + cl * 8;
            float acc[8];
#pragma unroll
            for (int j = 0; j < 8; ++j) acc[j] = 0.f;

#pragma unroll
            for (int k = 0; k < KNN; ++k) {
                const unsigned p = pks[k];
                const int idp = p & 0x7FF;
                const float w = __half2float(__ushort_as_half((unsigned short)(p >> 16)));
                const uint4 F = *(const uint4*)&sfb[(long)idp * CC + ch];  // 16B = 8 ch
                float2 f0 = unpack_h2(F.x), f1 = unpack_h2(F.y);
                float2 f2 = unpack_h2(F.z), f3 = unpack_h2(F.w);
                acc[0] = fmaf(w, f0.x, acc[0]);
                acc[1] = fmaf(w, f0.y, acc[1]);
                acc[2] = fmaf(w, f1.x, acc[2]);
                acc[3] = fmaf(w, f1.y, acc[3]);
                acc[4] = fmaf(w, f2.x, acc[4]);
                acc[5] = fmaf(w, f2.y, acc[5]);
                acc[6] = fmaf(w, f3.x, acc[6]);
                acc[7] = fmaf(w, f3.y, acc[7]);
            }
#pragma unroll
            for (int j = 0; j < 8; ++j)
                outq[(long)(ch + j) * NN] = acc[j];
        }
    }
}

extern "C" void kernel_launch(void* const* d_in, const int* in_sizes, int n_in,
                              void* d_out, int out_size, void* d_ws, size_t ws_size,
                              hipStream_t stream) {
    const float* xyz  = (const float*)d_in[0];   // [8,3,8192]
    const float* sxyz = (const float*)d_in[1];   // [8,3,2048]
    const float* sf   = (const float*)d_in[2];   // [8,256,2048]
    float* out = (float*)d_out;                  // [8,256,8192]

    unsigned short* gtile = (unsigned short*)d_ws;                        // 512 KB
    unsigned short* sft   = (unsigned short*)((char*)d_ws + 512 * 1024);  // 8 MB

    prep_kernel<<<dim3(BB * 32 * 4 + 64), dim3(256), 0, stream>>>(sf, sxyz, sft, gtile);
    knn_kernel<<<dim3(BB * NN / QPB), dim3(256), 0, stream>>>(xyz, sxyz, gtile, sft, out);
}

// Round 6
// 164.957 us; speedup vs baseline: 1.0872x; 1.0569x over previous
//
#include <hip/hip_runtime.h>
#include <hip/hip_fp16.h>

#define BB 8
#define NN 8192
#define SS 2048
#define CC 256
#define KNN 8
#define TOPM 10       // per-list candidate count (top-8 + margin 2 for key ties)
#define NLIST 4       // 4 lists per query (one per 16-lane MFMA row group)
#define QPB 64        // queries per block (16 per wave x 4 waves)
#define MSTRIDE 41    // mbuf per-query stride (u32s): 41 mod 32 = 9 -> conflict-free
#define P2STR 66      // prep LDS stride in halves: dword stride 33 (odd) -> conflict-free

#define UMIN(a, b) __builtin_elementwise_min(a, b)
#define UMAX(a, b) __builtin_elementwise_max(a, b)

typedef short bf16x8_t __attribute__((ext_vector_type(8)));   // 8 bf16 = 4 VGPR
typedef float f32x4_t __attribute__((ext_vector_type(4)));

__device__ __forceinline__ float2 unpack_h2(unsigned u) {
    __half2 h = *reinterpret_cast<__half2*>(&u);
    return __half22float2(h);
}

// f32 -> bf16 (RNE) and back, bit-level
__device__ __forceinline__ unsigned short f2bf(float f) {
    unsigned u = __float_as_uint(f);
    u += 0x7FFFu + ((u >> 16) & 1u);
    return (unsigned short)(u >> 16);
}
__device__ __forceinline__ float bf2f(unsigned short h) {
    return __uint_as_float((unsigned)h << 16);
}

// v_med3_u32: median of 3 (single VOP3). For ascending k[j-1]<=k[j]:
// med3(c, k[j-1], k[j]) == min(k[j], max(k[j-1], c)) == sorted-insert update.
__device__ __forceinline__ unsigned med3u(unsigned a, unsigned b, unsigned c) {
    unsigned d;
    asm("v_med3_u32 %0, %1, %2, %3" : "=v"(d) : "v"(a), "v"(b), "v"(c));
    return d;
}

// insert one candidate into ascending top-10: 9 independent med3 + 1 min
__device__ __forceinline__ void ins1(unsigned k1[TOPM], unsigned c) {
#pragma unroll
    for (int j = TOPM - 1; j >= 1; --j)
        k1[j] = med3u(c, k1[j - 1], k1[j]);
    k1[0] = UMIN(k1[0], c);
}

__device__ __forceinline__ void ins_step(unsigned k1[TOPM], f32x4_t d, unsigned sbase) {
    // key = truncated distance bits | point index (11 bits); d > 0 guaranteed (bias)
    ins1(k1, (__float_as_uint(d[0]) & 0xFFFFF800u) | sbase);
    ins1(k1, (__float_as_uint(d[1]) & 0xFFFFF800u) | (sbase + 1u));
    ins1(k1, (__float_as_uint(d[2]) & 0xFFFFF800u) | (sbase + 2u));
    ins1(k1, (__float_as_uint(d[3]) & 0xFFFFF800u) | (sbase + 3u));
}

// ---------------- Kernel P: fused prep (unchanged from round 5) -------------
// Blocks 0..1023:  64s x 64c tile transpose sf [B,C,S] f32 -> sfT [B,S,C] f16.
// Blocks 1024..1087: build split-bf16 MFMA A-tiles gt [B][2][SS][8].
__global__ __launch_bounds__(256) void prep_kernel(
    const float* __restrict__ sf,          // [B,C,S]
    const float* __restrict__ sxyz,        // [B,3,S]
    unsigned short* __restrict__ sft,      // [B][S][C] f16
    unsigned short* __restrict__ gt)       // [B][2][SS][8]
{
    __shared__ unsigned short ts[64 * P2STR];   // 8.25 KB

    const int blk = blockIdx.x;
    const int t   = threadIdx.x;

    if (blk < BB * 32 * 4) {
        const int b  = blk >> 7;
        const int st = (blk >> 2) & 31;
        const int c0 = (blk & 3) * 64;

        const int s  = t & 63;
        const int cq = t >> 6;
        const float* sfb = sf + ((long)b * CC + c0) * SS + st * 64;
#pragma unroll
        for (int it = 0; it < 16; ++it) {
            int c = it * 4 + cq;
            float v = sfb[(long)c * SS + s];                 // 256B/wave coalesced
            ts[s * P2STR + c] = __half_as_ushort(__float2half_rn(v));
        }
        __syncthreads();

        const int so = t >> 2;
        const int cl = t & 3;
        const unsigned short* src = &ts[so * P2STR + cl * 16];
        unsigned u[8];
#pragma unroll
        for (int i = 0; i < 8; ++i) u[i] = *(const unsigned*)&src[i * 2];
        unsigned short* dst = sft + ((long)b * SS + st * 64 + so) * CC + c0 + cl * 16;
        *(uint4*)&dst[0] = make_uint4(u[0], u[1], u[2], u[3]);
        *(uint4*)&dst[8] = make_uint4(u[4], u[5], u[6], u[7]);
    } else {
        const int idx = blk - BB * 32 * 4;
        const int b = idx >> 3;
        const int s = (idx & 7) * 256 + t;
        const float* sb = sxyz + (long)b * 3 * SS;
        unsigned short* gb = gt + (long)b * 2 * SS * 8;

        float px = sb[s], py = sb[SS + s], pz = sb[2 * SS + s];
        unsigned short xh = f2bf(px); unsigned short xl = f2bf(px - bf2f(xh));
        unsigned short yh = f2bf(py); unsigned short yl = f2bf(py - bf2f(yh));
        unsigned short zh = f2bf(pz); unsigned short zl = f2bf(pz - bf2f(zh));
        float pn = fmaf(px, px, fmaf(py, py, pz * pz));
        unsigned short nh = f2bf(pn); unsigned short nl = f2bf(pn - bf2f(nh));
        const unsigned ONE = 0x3F80u;
        // k0..7  = [xh, xl, xh, yh, yl, yh, zh, zl]
        uint4 t0 = make_uint4((unsigned)xh | ((unsigned)xl << 16),
                              (unsigned)xh | ((unsigned)yh << 16),
                              (unsigned)yl | ((unsigned)yh << 16),
                              (unsigned)zh | ((unsigned)zl << 16));
        // k8..15 = [zh, nh, nl, 1, 1, 0, 0, 0]
        uint4 t1 = make_uint4((unsigned)zh | ((unsigned)nh << 16),
                              (unsigned)nl | (ONE << 16),
                              ONE, 0u);
        *(uint4*)&gb[(long)s * 8] = t0;
        *(uint4*)&gb[((long)SS + s) * 8] = t1;
    }
}

// ---------------- Kernel A: MFMA KNN + fused IDW feature accumulation -------
// Phase 1: 128 MFMA steps, med3-insert top-10, prefetch distance 2 (no copies).
__global__ __launch_bounds__(256, 4) void knn_kernel(
    const float* __restrict__ xyz,         // [B,3,N]
    const float* __restrict__ sxyz,        // [B,3,S]
    const unsigned short* __restrict__ gt, // [B][2][SS][8] split-bf16 tiles
    const unsigned short* __restrict__ sft,// [B][S][C] f16 features
    float* __restrict__ out)               // [B,C,N]
{
    __shared__ unsigned mbuf[QPB * MSTRIDE];          // 10.25 KB
    __shared__ unsigned pk_lds[QPB * KNN];            // 2 KB

    const int b    = blockIdx.x >> 7;                 // 128 blocks per batch
    const int q0   = (blockIdx.x & 127) * QPB;
    const int tid  = threadIdx.x;
    const int wave = tid >> 6;
    const int lane = tid & 63;
    const int g    = lane >> 4;                       // MFMA row group / list id
    const int qi   = lane & 15;                       // query-in-wave / A-row

    const float* sb = sxyz + (long)b * 3 * SS;
    const float* xb = xyz + (long)b * 3 * NN;

    // ---- per-lane query B-fragment (col = lane&15, k = 8*g + e) ------------
    const int nq = q0 + wave * 16 + qi;
    const float qx = xb[nq], qy = xb[NN + nq], qz = xb[2 * NN + nq];

    bf16x8_t qf = (bf16x8_t)0;
    {
        unsigned short xh = f2bf(qx); float xhf = bf2f(xh);
        unsigned short yh = f2bf(qy); float yhf = bf2f(yh);
        unsigned short zh = f2bf(qz); float zhf = bf2f(zh);
        unsigned short xh2 = f2bf(-2.f * xhf), xl2 = f2bf(-2.f * (qx - xhf));
        unsigned short yh2 = f2bf(-2.f * yhf), yl2 = f2bf(-2.f * (qy - yhf));
        unsigned short zh2 = f2bf(-2.f * zhf), zl2 = f2bf(-2.f * (qz - zhf));
        float qn = fmaf(qx, qx, fmaf(qy, qy, qz * qz)) + 0.0625f;  // bias keeps d>0
        unsigned short nh = f2bf(qn); unsigned short nl = f2bf(qn - bf2f(nh));
        const short ONE = (short)0x3F80;
        if (g == 0) {
            qf[0] = (short)xh2; qf[1] = (short)xh2; qf[2] = (short)xl2;
            qf[3] = (short)yh2; qf[4] = (short)yh2; qf[5] = (short)yl2;
            qf[6] = (short)zh2; qf[7] = (short)zh2;
        } else if (g == 1) {
            qf[0] = (short)zl2; qf[1] = ONE; qf[2] = ONE;
            qf[3] = (short)nh;  qf[4] = (short)nl;
        } // g>=2: zero fragment (k16..31 unused -> A-slices don't matter)
    }

    // ---- phase 1: 128 MFMA steps, prefetch distance 2, med3 insertion ------
    const unsigned short* ap =
        gt + (long)b * 2 * SS * 8 + (long)(g & 1) * SS * 8 + qi * 8;

    unsigned k1[TOPM];
#pragma unroll
    for (int j = 0; j < TOPM; ++j) k1[j] = 0xFFFFFFFFu;

    const f32x4_t zacc = {0.f, 0.f, 0.f, 0.f};
    const unsigned ib4 = (unsigned)(g * 4);

    bf16x8_t a0 = *(const bf16x8_t*)ap; ap += 128;
    bf16x8_t a1 = *(const bf16x8_t*)ap; ap += 128;

    for (int step = 0; step < 126; step += 2) {
        f32x4_t d0 = __builtin_amdgcn_mfma_f32_16x16x32_bf16(a0, qf, zacc, 0, 0, 0);
        a0 = *(const bf16x8_t*)ap; ap += 128;        // load for step+2
        ins_step(k1, d0, ib4 + (unsigned)(step * 16));
        f32x4_t d1 = __builtin_amdgcn_mfma_f32_16x16x32_bf16(a1, qf, zacc, 0, 0, 0);
        a1 = *(const bf16x8_t*)ap; ap += 128;        // load for step+3
        ins_step(k1, d1, ib4 + (unsigned)((step + 1) * 16));
    }
    {
        f32x4_t d0 = __builtin_amdgcn_mfma_f32_16x16x32_bf16(a0, qf, zacc, 0, 0, 0);
        ins_step(k1, d0, ib4 + (unsigned)(126 * 16));
        f32x4_t d1 = __builtin_amdgcn_mfma_f32_16x16x32_bf16(a1, qf, zacc, 0, 0, 0);
        ins_step(k1, d1, ib4 + (unsigned)(127 * 16));
    }

    {
        unsigned* m1 = &mbuf[(wave * 16 + qi) * MSTRIDE + g * TOPM];
#pragma unroll
        for (int j = 0; j < TOPM; ++j) m1[j] = k1[j];
    }
    __syncthreads();

    // ---- phase 2: one thread per query, f64 re-rank of 40 candidates ------
    if (tid < QPB) {
        const int n2 = q0 + tid;
        const double dqx = (double)xb[n2], dqy = (double)xb[NN + n2], dqz = (double)xb[2 * NN + n2];
        const unsigned* ml = &mbuf[tid * MSTRIDE];

        unsigned long long top[KNN];
#pragma unroll
        for (int j = 0; j < KNN; ++j) top[j] = ~0ull;

#pragma unroll 4
        for (int j = 0; j < NLIST * TOPM; ++j) {
            unsigned key = ml[j];
            int s = key & 0x7FF;
            float px = sb[s], py = sb[SS + s], pz = sb[2 * SS + s];  // L2-hot
            double ex = (double)px - dqx;
            double ey = (double)py - dqy;
            double ez = (double)pz - dqz;
            double dd = ex * ex + ey * ey + ez * ez;
            unsigned long long c =
                (((unsigned long long)__double_as_longlong(dd)) & ~0x7FFull) | (unsigned long long)s;
#pragma unroll
            for (int jj = KNN - 1; jj >= 1; --jj)
                top[jj] = UMIN(UMAX(top[jj - 1], c), top[jj]);
            top[0] = UMIN(top[0], c);
        }

        // IDW weights (f32 math, f16-rounded weight as before)
        const float fqx = xb[n2], fqy = xb[NN + n2], fqz = xb[2 * NN + n2];
        int   id[KNN];
        float inv[KNN];
        float ssum = 0.f;
#pragma unroll
        for (int k = 0; k < KNN; ++k) {
            id[k] = (int)(top[k] & 0x7FFull);
            float px = sb[id[k]], py = sb[SS + id[k]], pz = sb[2 * SS + id[k]];
            float dx = px - fqx, dy = py - fqy, dz = pz - fqz;
            float dv = sqrtf(dx * dx + dy * dy + dz * dz);
            dv = fmaxf(dv, 1e-10f);
            inv[k] = 1.0f / dv;
            ssum += inv[k];
        }
        const float rs = 1.0f / ssum;
#pragma unroll
        for (int k = 0; k < KNN; ++k) {
            unsigned hw = (unsigned)__half_as_ushort(__float2half_rn(inv[k] * rs));
            pk_lds[tid * KNN + k] = (hw << 16) | (unsigned)id[k];
        }
    }
    __syncthreads();

    // ---- phase 3 (fused accum): thread = (query q, channel-lane cl) --------
    {
        const int q  = tid >> 2;
        const int cl = tid & 3;
        const unsigned short* sfb = sft + (long)b * SS * CC;
        float* outq = out + (long)b * CC * NN + (q0 + q);

        unsigned pks[KNN];
#pragma unroll
        for (int k = 0; k < KNN; ++k) pks[k] = pk_lds[q * KNN + k];  // LDS broadcast

#pragma unroll
        for (int cc = 0; cc < 8; ++cc) {
            const int ch = cc * 32 + cl * 8;
            float acc[8];
#pragma unroll
            for (int j = 0; j < 8; ++j) acc[j] = 0.f;

#pragma unroll
            for (int k = 0; k < KNN; ++k) {
                const unsigned p = pks[k];
                const int idp = p & 0x7FF;
                const float w = __half2float(__ushort_as_half((unsigned short)(p >> 16)));
                const uint4 F = *(const uint4*)&sfb[(long)idp * CC + ch];  // 16B = 8 ch
                float2 f0 = unpack_h2(F.x), f1 = unpack_h2(F.y);
                float2 f2 = unpack_h2(F.z), f3 = unpack_h2(F.w);
                acc[0] = fmaf(w, f0.x, acc[0]);
                acc[1] = fmaf(w, f0.y, acc[1]);
                acc[2] = fmaf(w, f1.x, acc[2]);
                acc[3] = fmaf(w, f1.y, acc[3]);
                acc[4] = fmaf(w, f2.x, acc[4]);
                acc[5] = fmaf(w, f2.y, acc[5]);
                acc[6] = fmaf(w, f3.x, acc[6]);
                acc[7] = fmaf(w, f3.y, acc[7]);
            }
#pragma unroll
            for (int j = 0; j < 8; ++j)
                outq[(long)(ch + j) * NN] = acc[j];
        }
    }
}

extern "C" void kernel_launch(void* const* d_in, const int* in_sizes, int n_in,
                              void* d_out, int out_size, void* d_ws, size_t ws_size,
                              hipStream_t stream) {
    const float* xyz  = (const float*)d_in[0];   // [8,3,8192]
    const float* sxyz = (const float*)d_in[1];   // [8,3,2048]
    const float* sf   = (const float*)d_in[2];   // [8,256,2048]
    float* out = (float*)d_out;                  // [8,256,8192]

    unsigned short* gtile = (unsigned short*)d_ws;                        // 512 KB
    unsigned short* sft   = (unsigned short*)((char*)d_ws + 512 * 1024);  // 8 MB

    prep_kernel<<<dim3(BB * 32 * 4 + 64), dim3(256), 0, stream>>>(sf, sxyz, sft, gtile);
    knn_kernel<<<dim3(BB * NN / QPB), dim3(256), 0, stream>>>(xyz, sxyz, gtile, sft, out);
}